// Round 10
// baseline (239.326 us; speedup 1.0000x reference)
//
#include <hip/hip_runtime.h>

typedef float v2f __attribute__((ext_vector_type(2)));

#define NT 256   // threads per block
#define NR 16    // v2f amplitudes per register tile (4-bit window)

// ---------------------------------------------------------------------------
// LDS swizzle: l ^ ((l>>5)&31) -- measured ~free (2-way max) on all maps.
__device__ __forceinline__ int swz(int l) { return l ^ ((l >> 5) & 31); }

// SU(2) rotation on a register pair: U = [[a, b], [-conj(b), conj(a)]]
__device__ __forceinline__ void rot2(v2f& x, v2f& y, v2f aa, v2f an, v2f bb, v2f bn) {
  v2f xs = __builtin_shufflevector(x, x, 1, 0);
  v2f ys = __builtin_shufflevector(y, y, 1, 0);
  v2f n0 = aa * x + an * xs + bb * y + bn * ys;
  v2f n1 = aa * y - an * ys + bn * xs - bb * x;
  x = n0;
  y = n1;
}

#define ROTS(S, T, G)                                                          \
  do {                                                                         \
    const float4 u = Utab[G];                                                  \
    const v2f aa = {u.x, u.x}, an = {-u.y, u.y};                               \
    const v2f bb = {u.z, u.z}, bn = {-u.w, u.w};                               \
    _Pragma("unroll") for (int v = 0; v < NR; ++v) if (!((v >> (T)) & 1))      \
        rot2(S[v], S[v | (1 << (T))], aa, an, bb, bn);                         \
  } while (0)

// CNOT (control C, target T reg-bits): compile-time register swap.
#define CNOTS(S, C, T)                                                         \
  do {                                                                         \
    _Pragma("unroll") for (int v = 0; v < NR; ++v)                             \
        if (((v >> (C)) & 1) && !((v >> (T)) & 1)) {                           \
      v2f tmp = S[v];                                                          \
      S[v] = S[v | (1 << (T))];                                                \
      S[v | (1 << (T))] = tmp;                                                 \
    }                                                                          \
  } while (0)

// Window maps: 12-bit local index c from (t[7:0], reg v[3:0]).
// Wave bits c11..10 = t7..6 for W2,W3,W4,B3,C4,D63 (wave-local);
// only W1 (c11..8 = v) crosses waves.
#define MAP_W1(t, v)  (((v) << 8) | (t))                               // reg = c11..8
#define MAP_W2(t, v)  ((((t) >> 5) << 9) | ((v) << 5) | ((t) & 31))    // reg = c8..5
#define MAP_W3(t, v)  ((((t) >> 2) << 6) | ((v) << 2) | ((t) & 3))     // reg = c5..2
#define MAP_W4(t, v)  (((t) << 4) | (v))                               // reg = c3..0
#define MAP_B3(t, v)  ((((t) >> 1) << 5) | ((v) << 1) | ((t) & 1))     // reg = c4..1
#define MAP_C4(t, v)  ((((t) >> 4) << 8) | ((v) << 4) | ((t) & 15))    // reg = c7..4
#define MAP_D63(t, v) ((((t) >> 3) << 7) | ((v) << 3) | ((t) & 7))     // reg = c6..3

// Write/read a register tile S through LDS buffer L with map M.
#define WM(S, L, M) _Pragma("unroll") for (int r = 0; r < NR; ++r) L[swz(M(tid, r))] = S[r]
#define RM(S, L, M) _Pragma("unroll") for (int v = 0; v < NR; ++v) S[v] = L[swz(M(tid, v))]

// ---------------------------------------------------------------------------
// passA gate groups (layer l compile-time). Wire q <-> local bit 11-q.
#define GA1(S, l)                                                              \
  do { ROTS(S, 3, (l)*16 + 0); ROTS(S, 2, (l)*16 + 1); ROTS(S, 1, (l)*16 + 2); \
       ROTS(S, 0, (l)*16 + 3); CNOTS(S, 3, 2); CNOTS(S, 2, 1); CNOTS(S, 1, 0); } while (0)
#define GA2(S, l)                                                              \
  do { ROTS(S, 2, (l)*16 + 4); ROTS(S, 1, (l)*16 + 5); ROTS(S, 0, (l)*16 + 6); \
       CNOTS(S, 3, 2); CNOTS(S, 2, 1); CNOTS(S, 1, 0); } while (0)
#define GA3(S, l)                                                              \
  do { ROTS(S, 2, (l)*16 + 7); ROTS(S, 1, (l)*16 + 8);                         \
       if ((l) <= 2) ROTS(S, 0, (l)*16 + 9);                                   \
       CNOTS(S, 3, 2); CNOTS(S, 2, 1);                                         \
       if ((l) <= 2) CNOTS(S, 1, 0); } while (0)
#define GA4(S, l)                                                              \
  do { if ((l) == 0) { ROTS(S, 1, 10); ROTS(S, 0, 11); CNOTS(S, 2, 1); CNOTS(S, 1, 0); } \
       else          { ROTS(S, 1, 26); CNOTS(S, 2, 1); } } while (0)

// passB gate groups (wire q <-> local bit 15-q; same schedule as r8).
#define GPRE(S) do { ROTS(S,3,12); ROTS(S,2,13); ROTS(S,1,14); ROTS(S,0,15); } while (0)
#define GQ0(S)  do { CNOTS(S,3,2); CNOTS(S,2,1); CNOTS(S,1,0);                 \
                     ROTS(S,3,27); ROTS(S,2,28); ROTS(S,1,29); } while (0)
#define GQ1(S)  do { CNOTS(S,1,0); ROTS(S,1,30); ROTS(S,0,31); } while (0)
#define GD0(S)  do { CNOTS(S,1,0); ROTS(S,1,42); CNOTS(S,2,1); ROTS(S,2,57); CNOTS(S,3,2); } while (0)
#define GD1(S)  do { CNOTS(S,1,0); ROTS(S,1,43); CNOTS(S,2,1); ROTS(S,2,58); CNOTS(S,3,2); } while (0)
#define GD2(S)  do { CNOTS(S,1,0); ROTS(S,1,44); CNOTS(S,2,1); ROTS(S,2,59); CNOTS(S,3,2); } while (0)
#define GD3(S)  do { CNOTS(S,1,0); ROTS(S,1,45); CNOTS(S,2,1); ROTS(S,2,60); CNOTS(S,3,2); } while (0)
#define GD4(S)  do { CNOTS(S,1,0); ROTS(S,1,46); ROTS(S,0,47);                 \
                     CNOTS(S,2,1); CNOTS(S,1,0);                               \
                     ROTS(S,2,61); ROTS(S,1,62); ROTS(S,0,63);                 \
                     CNOTS(S,3,2); CNOTS(S,2,1); CNOTS(S,1,0); } while (0)

// Epilogue per tile: probs, per-wire signed partials, wave shfl-reduce.
#define EPIV(S, VALS)                                                          \
  do {                                                                         \
    float P = 0.f, f12 = 0.f, f13 = 0.f, f14 = 0.f, f15 = 0.f;                 \
    _Pragma("unroll") for (int v = 0; v < NR; ++v) {                           \
      float p = S[v][0] * S[v][0] + S[v][1] * S[v][1];                         \
      P += p;                                                                  \
      f12 += ((v >> 3) & 1) ? -p : p;                                          \
      f13 += ((v >> 2) & 1) ? -p : p;                                          \
      f14 += ((v >> 1) & 1) ? -p : p;                                          \
      f15 += ((v >> 0) & 1) ? -p : p;                                          \
    }                                                                          \
    VALS[0] = P;                                                               \
    _Pragma("unroll") for (int q = 4; q <= 11; ++q)                            \
      VALS[q - 3] = ((tid >> (11 - q)) & 1) ? -P : P;                          \
    VALS[9] = f12; VALS[10] = f13; VALS[11] = f14; VALS[12] = f15;             \
    _Pragma("unroll") for (int q = 0; q < 13; ++q) {                           \
      float x = VALS[q];                                                       \
      _Pragma("unroll") for (int m = 1; m < 64; m <<= 1) x += __shfl_xor(x, m, 64); \
      VALS[q] = x;                                                             \
    }                                                                          \
  } while (0)

// ---------------------------------------------------------------------------
// Fused U = RZ @ RY @ RX per (layer, wire): (alpha_re, alpha_im, beta_re, beta_im)
__global__ void k_setup(const float* __restrict__ params, float4* __restrict__ Utab) {
  int g = threadIdx.x;
  if (g < 64) {
    float a = params[g * 3 + 0] * 0.5f;
    float b = params[g * 3 + 1] * 0.5f;
    float c = params[g * 3 + 2] * 0.5f;
    float sa, ca, sb, cb, sc, cc;
    sincosf(a, &sa, &ca);
    sincosf(b, &sb, &cb);
    sincosf(c, &sc, &cc);
    float X = cb * ca, Y = sb * sa;
    float Xp = -sb * ca, Yp = -cb * sa;
    Utab[g] = make_float4(cc * X + sc * Y, cc * Y - sc * X,
                          cc * Xp + sc * Yp, cc * Yp - sc * Xp);
  }
}

// ---------------------------------------------------------------------------
// Pass A: local wires 0..11 (orig bits 15..4). TWO tiles/block (chunks 2j,
// 2j+1), each with its own 32 KB LDS buffer; DS of one tile hides under the
// other tile's gate VALU (within-wave software pipeline).
__global__ __launch_bounds__(NT, 2) void k_passA(const float* __restrict__ in,
                                                 const float4* __restrict__ Utab,
                                                 float4* __restrict__ st) {
  __shared__ v2f lds0[4096];
  __shared__ v2f lds1[4096];
  const int tid = threadIdx.x;
  // XCD grouping: the 8 j-siblings of batch b adjacent on one XCD.
  const int xcd = blockIdx.x & 7;
  const int y = blockIdx.x >> 3;
  const int j = y & 7;                       // chunk pair: g = 2j, 2j+1
  const int b = xcd | ((y >> 3) << 3);
  const float* base = in + (size_t)b * 65536 + 2 * j;

  v2f s0[NR], s1[NR];
  // W1 arrangement: local c = v<<8|tid, orig = c<<4 | g. float2 covers g=2j,2j+1.
#pragma unroll
  for (int v = 0; v < NR; ++v) {
    float2 f = *(const float2*)(base + (((v << 8) | tid) << 4));
    s0[v] = v2f{f.x, 0.0f};
    s1[v] = v2f{f.y, 0.0f};
  }

#pragma unroll
  for (int l = 0; l < 4; ++l) {
    GA1(s0, l); GA1(s1, l);
    __syncthreads();                         // W1 edge: cross-wave scatter
    WM(s0, lds0, MAP_W1); WM(s1, lds1, MAP_W1);
    __syncthreads();
    RM(s0, lds0, MAP_W2); GA2(s0, l);
    WM(s0, lds0, MAP_W2);
    RM(s1, lds1, MAP_W2); GA2(s1, l);        // covers R(s0,W3)'s writes
    WM(s1, lds1, MAP_W2);
    RM(s0, lds0, MAP_W3); GA3(s0, l);        // covers R(s1,W3)'s writes
    if (l <= 1) {
      WM(s0, lds0, MAP_W3);
      RM(s1, lds1, MAP_W3); GA3(s1, l);      // covers R(s0,W4)
      WM(s1, lds1, MAP_W3);
      RM(s0, lds0, MAP_W4); GA4(s0, l);      // covers R(s1,W4)
      WM(s0, lds0, MAP_W4);
      RM(s1, lds1, MAP_W4); GA4(s1, l);
      WM(s1, lds1, MAP_W4);
      __syncthreads();                       // WB edge -> W1 cross reads
      RM(s0, lds0, MAP_W1); RM(s1, lds1, MAP_W1);
    } else if (l == 2) {
      WM(s0, lds0, MAP_W3);
      RM(s1, lds1, MAP_W3); GA3(s1, l);
      WM(s1, lds1, MAP_W3);
      __syncthreads();
      RM(s0, lds0, MAP_W1); RM(s1, lds1, MAP_W1);
    } else {                                 // l == 3: last window
      RM(s1, lds1, MAP_W3); GA3(s1, l);
    }
  }

  // Exit: both tiles (W3 arr) -> LDS, bar, combined float4 stores.
  // st float4 index: b*32768 + j*4096 + m  holds amps (m<<4|2j, m<<4|2j+1).
  WM(s0, lds0, MAP_W3); WM(s1, lds1, MAP_W3);
  __syncthreads();
  float4* outp = st + ((size_t)b << 15) + (j << 12);
#pragma unroll
  for (int k = 0; k < 16; ++k) {
    int m = (k << 8) | tid;
    v2f a = lds0[swz(m)], c = lds1[swz(m)];
    outp[m] = make_float4(a[0], a[1], c[0], c[1]);
  }
}

// ---------------------------------------------------------------------------
// Pass B: local wires 4..15 (orig bits 11..0). TWO tiles/block (h = 2i, 2i+1).
// All remaps wave-local -> zero barriers in the pipeline.
__global__ __launch_bounds__(NT, 2) void k_passB(const float4* __restrict__ st,
                                                 const float4* __restrict__ Utab,
                                                 float* __restrict__ partials) {
  __shared__ v2f lds0[4096];
  __shared__ v2f lds1[4096];
  const int tid = threadIdx.x;
  const int b = blockIdx.x >> 3;
  const int i = blockIdx.x & 7;
  const int h0 = 2 * i, h1 = 2 * i + 1;
  const float4* base4 = st + ((size_t)b << 15);

  // W4 arrangement entry: float4 (g2, m) holds chunks 2g2, 2g2+1 of amp m.
  v2f s0[NR], s1[NR];
#pragma unroll
  for (int g2 = 0; g2 < 8; ++g2) {
    float4 f = base4[(g2 << 12) + (h0 << 8) + tid];
    s0[2 * g2]     = v2f{f.x, f.y};
    s0[2 * g2 + 1] = v2f{f.z, f.w};
  }
#pragma unroll
  for (int g2 = 0; g2 < 8; ++g2) {
    float4 f = base4[(g2 << 12) + (h1 << 8) + tid];
    s1[2 * g2]     = v2f{f.x, f.y};
    s1[2 * g2 + 1] = v2f{f.z, f.w};
  }

  // Edges: E1 W4->B3, E2 B3->W4, E3 W4->C4, E4 C4->D63, E5 D63->W3,
  //        E6 W3->B3, E7 B3->W4.  Alternating two-tile pipeline.
  GPRE(s0); WM(s0, lds0, MAP_W4);
  GPRE(s1);
  RM(s0, lds0, MAP_B3);  WM(s1, lds1, MAP_W4);
  GQ0(s0);  WM(s0, lds0, MAP_B3);
  RM(s1, lds1, MAP_B3);
  GQ0(s1);
  RM(s0, lds0, MAP_W4);  WM(s1, lds1, MAP_B3);
  GQ1(s0);  WM(s0, lds0, MAP_W4);
  RM(s1, lds1, MAP_W4);
  GQ1(s1);
  RM(s0, lds0, MAP_C4);  WM(s1, lds1, MAP_W4);
  GD0(s0);  WM(s0, lds0, MAP_C4);
  RM(s1, lds1, MAP_C4);
  GD0(s1);
  RM(s0, lds0, MAP_D63); WM(s1, lds1, MAP_C4);
  GD1(s0);  WM(s0, lds0, MAP_D63);
  RM(s1, lds1, MAP_D63);
  GD1(s1);
  RM(s0, lds0, MAP_W3);  WM(s1, lds1, MAP_D63);
  GD2(s0);  WM(s0, lds0, MAP_W3);
  RM(s1, lds1, MAP_W3);
  GD2(s1);
  RM(s0, lds0, MAP_B3);  WM(s1, lds1, MAP_W3);
  GD3(s0);  WM(s0, lds0, MAP_B3);
  RM(s1, lds1, MAP_B3);
  GD3(s1);
  RM(s0, lds0, MAP_W4);  WM(s1, lds1, MAP_B3);
  GD4(s0);
  RM(s1, lds1, MAP_W4);
  GD4(s1);

  // Epilogue (W4 arr): c = t<<4|v; wires 12..15 <-> v3..0; 4..11 <-> t7..0;
  // wires 0..3 <-> h bits 3..0.
  float vals0[13], vals1[13];
  EPIV(s0, vals0);
  EPIV(s1, vals1);

  const int lane = tid & 63, w = tid >> 6;
  __syncthreads();  // waves' prior LDS reads done before red[] reuse
  float* red0 = (float*)lds0;
  float* red1 = (float*)lds1;
  if (lane == 0) {
#pragma unroll
    for (int q = 0; q < 13; ++q) { red0[q * 4 + w] = vals0[q]; red1[q * 4 + w] = vals1[q]; }
  }
  __syncthreads();
  if (tid < 13) {
    float F0 = 0.f, F1 = 0.f;
#pragma unroll
    for (int ww = 0; ww < 4; ++ww) { F0 += red0[tid * 4 + ww]; F1 += red1[tid * 4 + ww]; }
    float* pt0 = partials + ((size_t)(b * 16 + h0)) * 16;
    float* pt1 = partials + ((size_t)(b * 16 + h1)) * 16;
    if (tid == 0) {
      pt0[0] = (h0 & 8) ? -F0 : F0;  pt1[0] = (h1 & 8) ? -F1 : F1;
      pt0[1] = (h0 & 4) ? -F0 : F0;  pt1[1] = (h1 & 4) ? -F1 : F1;
      pt0[2] = (h0 & 2) ? -F0 : F0;  pt1[2] = (h1 & 2) ? -F1 : F1;
      pt0[3] = (h0 & 1) ? -F0 : F0;  pt1[3] = (h1 & 1) ? -F1 : F1;
    } else {
      pt0[tid + 3] = F0;             // tid 1..8 -> wires 4..11; 9..12 -> 12..15
      pt1[tid + 3] = F1;
    }
  }
}

// ---------------------------------------------------------------------------
__global__ void k_head(const float* __restrict__ partials, const float* __restrict__ w,
                       const float* __restrict__ bh, float* __restrict__ out) {
  int b = threadIdx.x;  // 256 threads
  float acc = bh[0];
  for (int q = 0; q < 16; ++q) {
    float F = 0.f;
    for (int hh = 0; hh < 16; ++hh) F += partials[(size_t)(b * 16 + hh) * 16 + q];
    acc += w[q] * F;
  }
  out[b] = acc;
}

// ---------------------------------------------------------------------------
extern "C" void kernel_launch(void* const* d_in, const int* in_sizes, int n_in,
                              void* d_out, int out_size, void* d_ws, size_t ws_size,
                              hipStream_t stream) {
  const float* state  = (const float*)d_in[0];
  const float* params = (const float*)d_in[1];
  const float* w_head = (const float*)d_in[2];
  const float* b_head = (const float*)d_in[3];
  float* out = (float*)d_out;

  char* ws = (char*)d_ws;
  float4* st = (float4*)ws;                                 // 128 MB
  float4* Utab = (float4*)(ws + (size_t)134217728);         // 1 KB
  float* partials = (float*)(ws + (size_t)134217728 + 1024);// 256 KB

  k_setup<<<1, 64, 0, stream>>>(params, Utab);
  k_passA<<<dim3(2048), dim3(NT), 0, stream>>>(state, Utab, st);
  k_passB<<<dim3(2048), dim3(NT), 0, stream>>>(st, Utab, partials);
  k_head<<<1, 256, 0, stream>>>(partials, w_head, b_head, out);
}

// Round 11
// 216.079 us; speedup vs baseline: 1.1076x; 1.1076x over previous
//
#include <hip/hip_runtime.h>

typedef float v2f __attribute__((ext_vector_type(2)));

#define NTA 256  // passA threads
#define NTB 512  // passB threads
#define NR 16    // v2f amplitudes per thread (4-bit register window)

// ---------------------------------------------------------------------------
// LDS swizzle: l ^ ((l>>5)&31) -- measured ~free (2-way max) on all maps.
__device__ __forceinline__ int swz(int l) { return l ^ ((l >> 5) & 31); }

// SU(2) rotation on a register pair: U = [[a, b], [-conj(b), conj(a)]]
__device__ __forceinline__ void rot2(v2f& x, v2f& y, v2f aa, v2f an, v2f bb, v2f bn) {
  v2f xs = __builtin_shufflevector(x, x, 1, 0);
  v2f ys = __builtin_shufflevector(y, y, 1, 0);
  v2f n0 = aa * x + an * xs + bb * y + bn * ys;
  v2f n1 = aa * y - an * ys + bn * xs - bb * x;
  x = n0;
  y = n1;
}

#define ROTS(S, T, G)                                                          \
  do {                                                                         \
    const float4 u = Utab[G];                                                  \
    const v2f aa = {u.x, u.x}, an = {-u.y, u.y};                               \
    const v2f bb = {u.z, u.z}, bn = {-u.w, u.w};                               \
    _Pragma("unroll") for (int v = 0; v < NR; ++v) if (!((v >> (T)) & 1))      \
        rot2(S[v], S[v | (1 << (T))], aa, an, bb, bn);                         \
  } while (0)

// CNOT (control C, target T reg-bits): compile-time register swap.
#define CNOTS(S, C, T)                                                         \
  do {                                                                         \
    _Pragma("unroll") for (int v = 0; v < NR; ++v)                             \
        if (((v >> (C)) & 1) && !((v >> (T)) & 1)) {                           \
      v2f tmp = S[v];                                                          \
      S[v] = S[v | (1 << (T))];                                                \
      S[v | (1 << (T))] = tmp;                                                 \
    }                                                                          \
  } while (0)

// passA maps: 12-bit local c from (t[7:0], v[3:0]). Wave bits c11..10 = t7..6
// for W2..W4 (wave-local); W1 (reg = c11..8) crosses waves.
#define MAP_W1(t, v)  (((v) << 8) | (t))                               // reg = c11..8
#define MAP_W2(t, v)  ((((t) >> 5) << 9) | ((v) << 5) | ((t) & 31))    // reg = c8..5
#define MAP_W3(t, v)  ((((t) >> 2) << 6) | ((v) << 2) | ((t) & 3))     // reg = c5..2
#define MAP_W4(t, v)  (((t) << 4) | (v))                               // reg = c3..0

// passB maps: 13-bit local c from (t[8:0], v[3:0]). ALL keep c12..10 = t8..6
// -> every remap is wave-local, zero barriers.
#define M40(t, v) (((t) << 4) | (v))                                   // reg = c3..0
#define M41(t, v) ((((t) >> 1) << 5) | ((v) << 1) | ((t) & 1))         // reg = c4..1
#define M52(t, v) ((((t) >> 2) << 6) | ((v) << 2) | ((t) & 3))         // reg = c5..2
#define M63(t, v) ((((t) >> 3) << 7) | ((v) << 3) | ((t) & 7))         // reg = c6..3
#define M74(t, v) ((((t) >> 4) << 8) | ((v) << 4) | ((t) & 15))        // reg = c7..4

// Write/read a register tile S through LDS buffer L with map M.
#define WM(S, L, M) _Pragma("unroll") for (int r = 0; r < NR; ++r) L[swz(M(tid, r))] = S[r]
#define RM(S, L, M) _Pragma("unroll") for (int v = 0; v < NR; ++v) S[v] = L[swz(M(tid, v))]

// passB gate groups (wire q <-> local bit 15-q; verified r8/r10 schedule).
#define GPRE(S) do { ROTS(S,3,12); ROTS(S,2,13); ROTS(S,1,14); ROTS(S,0,15); } while (0)
#define GQ0(S)  do { CNOTS(S,3,2); CNOTS(S,2,1); CNOTS(S,1,0);                 \
                     ROTS(S,3,27); ROTS(S,2,28); ROTS(S,1,29); } while (0)
#define GQ1(S)  do { CNOTS(S,1,0); ROTS(S,1,30); ROTS(S,0,31); } while (0)
#define GD0(S)  do { CNOTS(S,1,0); ROTS(S,1,42); CNOTS(S,2,1); ROTS(S,2,57); CNOTS(S,3,2); } while (0)
#define GD1(S)  do { CNOTS(S,1,0); ROTS(S,1,43); CNOTS(S,2,1); ROTS(S,2,58); CNOTS(S,3,2); } while (0)
#define GD2(S)  do { CNOTS(S,1,0); ROTS(S,1,44); CNOTS(S,2,1); ROTS(S,2,59); CNOTS(S,3,2); } while (0)
#define GD3(S)  do { CNOTS(S,1,0); ROTS(S,1,45); CNOTS(S,2,1); ROTS(S,2,60); CNOTS(S,3,2); } while (0)
#define GD4(S)  do { CNOTS(S,1,0); ROTS(S,1,46); ROTS(S,0,47);                 \
                     CNOTS(S,2,1); CNOTS(S,1,0);                               \
                     ROTS(S,2,61); ROTS(S,1,62); ROTS(S,0,63);                 \
                     CNOTS(S,3,2); CNOTS(S,2,1); CNOTS(S,1,0); } while (0)

// ---------------------------------------------------------------------------
// Fused U = RZ @ RY @ RX per (layer, wire): (alpha_re, alpha_im, beta_re, beta_im)
__global__ void k_setup(const float* __restrict__ params, float4* __restrict__ Utab) {
  int g = threadIdx.x;
  if (g < 64) {
    float a = params[g * 3 + 0] * 0.5f;
    float b = params[g * 3 + 1] * 0.5f;
    float c = params[g * 3 + 2] * 0.5f;
    float sa, ca, sb, cb, sc, cc;
    sincosf(a, &sa, &ca);
    sincosf(b, &sb, &cb);
    sincosf(c, &sc, &cc);
    float X = cb * ca, Y = sb * sa;
    float Xp = -sb * ca, Yp = -cb * sa;
    Utab[g] = make_float4(cc * X + sc * Y, cc * Y - sc * X,
                          cc * Xp + sc * Yp, cc * Yp - sc * Xp);
  }
}

// ---------------------------------------------------------------------------
// Pass A (r8 verbatim): local wires 0..11 (orig bits 15..4); wire q <-> bit 11-q.
// Executes R_l(q <= 11-l), C_l(q,q+1) for q <= 10-l. 32 KB tile, 4 blocks/CU.
__global__ __launch_bounds__(NTA, 4) void k_passA(const float* __restrict__ in,
                                                  const float4* __restrict__ Utab,
                                                  v2f* __restrict__ st) {
  __shared__ v2f lds2[4096];
  const int tid = threadIdx.x;
  // XCD grouping: all 16 g-siblings of batch b on one XCD, adjacent slots.
  const int xcd = blockIdx.x & 7;
  const int y = blockIdx.x >> 3;
  const int g = y & 15;
  const int b = xcd | ((y >> 4) << 3);
  const float* base = in + (size_t)b * 65536;

  v2f s[NR];
  // Direct load in W1 arrangement: orig = v<<12 | tid<<4 | g.
#pragma unroll
  for (int v = 0; v < NR; ++v) {
    float re = base[(v << 12) + (tid << 4) + g];
    s[v] = v2f{re, 0.0f};
  }

#pragma unroll
  for (int l = 0; l < 4; ++l) {
    // W1: reg c11..8 = wires 0..3 (T = 3-q)
    ROTS(s, 3, l * 16 + 0); ROTS(s, 2, l * 16 + 1); ROTS(s, 1, l * 16 + 2);
    ROTS(s, 0, l * 16 + 3);
    CNOTS(s, 3, 2); CNOTS(s, 2, 1); CNOTS(s, 1, 0);   // C_l (0,1),(1,2),(2,3)
    __syncthreads();                                   // W1 cross-wave scatter
    WM(s, lds2, MAP_W1);
    __syncthreads();
    RM(s, lds2, MAP_W2);
    // W2: reg c8..5 = wires 3..6; rotations on 4,5,6 (T = 6-q)
    ROTS(s, 2, l * 16 + 4); ROTS(s, 1, l * 16 + 5); ROTS(s, 0, l * 16 + 6);
    CNOTS(s, 3, 2); CNOTS(s, 2, 1); CNOTS(s, 1, 0);   // C_l (3,4),(4,5),(5,6)
    WM(s, lds2, MAP_W2); RM(s, lds2, MAP_W3);          // wave-local
    // W3: reg c5..2 = wires 6..9 (T = 9-q); staircase trims l=2,3
    ROTS(s, 2, l * 16 + 7); ROTS(s, 1, l * 16 + 8);
    if (l <= 2) ROTS(s, 0, l * 16 + 9);
    CNOTS(s, 3, 2); CNOTS(s, 2, 1);                    // C_l (6,7),(7,8)
    if (l <= 2) CNOTS(s, 1, 0);                        // C_l (8,9)
    if (l <= 1) {
      WM(s, lds2, MAP_W3); RM(s, lds2, MAP_W4);        // wave-local
      // W4: reg c3..0 = wires 8..11 (T = 11-q); staircase tail
      if (l == 0) { ROTS(s, 1, 10); ROTS(s, 0, 11); CNOTS(s, 2, 1); CNOTS(s, 1, 0); }
      else        { ROTS(s, 1, 26); CNOTS(s, 2, 1); }
      WM(s, lds2, MAP_W4);
      __syncthreads();                                 // -> W1 cross read
      RM(s, lds2, MAP_W1);
    } else if (l == 2) {
      WM(s, lds2, MAP_W3);
      __syncthreads();
      RM(s, lds2, MAP_W1);
    }
  }

  // Exit (W3 arrangement): own-region write, barrier, paired-interleave stores
  // st[b][g>>1][m][g&1] (v2f units) so passB reads are float4-coalesced.
  WM(s, lds2, MAP_W3);
  __syncthreads();
  v2f* outp = st + (size_t)b * 65536 + ((g >> 1) << 13) + (g & 1);
#pragma unroll
  for (int k = 0; k < 16; ++k) {
    int m = (k << 8) | tid;
    outp[m << 1] = lds2[swz(m)];
  }
}

// ---------------------------------------------------------------------------
// Pass B: 512 threads, 64 KB tile, local wires 3..15 (orig bits 12..0);
// wire q <-> local bit 15-q. Remaining staircase ops all in bits 7..0; every
// remap wave-local (c12..10 = t8..6 under all maps) -> zero barriers.
// h = orig bits 15..13 (8 blocks/batch).
__global__ __launch_bounds__(NTB, 2) void k_passB(const float4* __restrict__ st4,
                                                  const float4* __restrict__ Utab,
                                                  float* __restrict__ partials) {
  __shared__ v2f lds2[8192];
  const int tid = threadIdx.x;
  const int b = blockIdx.x >> 3;
  const int h = blockIdx.x & 7;
  const float4* base4 = st4 + (size_t)b * 32768;

  // Coalesced float4 entry in M40 arrangement: float4 (g2, m) holds chunks
  // 2g2, 2g2+1 of amp row m = h<<9 | tid; s[v] = amp (m<<4)|v.
  v2f s[NR];
#pragma unroll
  for (int g2 = 0; g2 < 8; ++g2) {
    float4 f = base4[(g2 << 12) + (h << 9) + tid];
    s[2 * g2]     = v2f{f.x, f.y};
    s[2 * g2 + 1] = v2f{f.z, f.w};
  }

  GPRE(s);                              // R0 w12..15          (bits 3..0)
  WM(s, lds2, M40); RM(s, lds2, M41);
  GQ0(s);                               // C0 head + R1 w11..13 (bits 4..1)
  WM(s, lds2, M41); RM(s, lds2, M40);
  GQ1(s);                               // C0(14,15), R1 w14,15 (bits 3..0)
  WM(s, lds2, M40); RM(s, lds2, M74);
  GD0(s);                               // diag: w10/9/8 links  (bits 7..4)
  WM(s, lds2, M74); RM(s, lds2, M63);
  GD1(s);                               //                      (bits 6..3)
  WM(s, lds2, M63); RM(s, lds2, M52);
  GD2(s);                               //                      (bits 5..2)
  WM(s, lds2, M52); RM(s, lds2, M41);
  GD3(s);                               //                      (bits 4..1)
  WM(s, lds2, M41); RM(s, lds2, M40);
  GD4(s);                               // chain tails          (bits 3..0)

  // Epilogue (M40 arrangement): c = t<<4|v; wires 12..15 <-> v3..0,
  // wires 3..11 <-> t8..0 (wire q <-> t bit 11-q), wires 0..2 <-> h bits 2..0.
  float P = 0.f, f12 = 0.f, f13 = 0.f, f14 = 0.f, f15 = 0.f;
#pragma unroll
  for (int v = 0; v < NR; ++v) {
    float p = s[v][0] * s[v][0] + s[v][1] * s[v][1];
    P += p;
    f12 += ((v >> 3) & 1) ? -p : p;
    f13 += ((v >> 2) & 1) ? -p : p;
    f14 += ((v >> 1) & 1) ? -p : p;
    f15 += ((v >> 0) & 1) ? -p : p;
  }
  float vals[14];
  vals[0] = P;
#pragma unroll
  for (int q = 3; q <= 11; ++q)
    vals[q - 2] = ((tid >> (11 - q)) & 1) ? -P : P;
  vals[10] = f12; vals[11] = f13; vals[12] = f14; vals[13] = f15;

  const int lane = tid & 63, w = tid >> 6;
#pragma unroll
  for (int q = 0; q < 14; ++q) {
    float x = vals[q];
#pragma unroll
    for (int m = 1; m < 64; m <<= 1) x += __shfl_xor(x, m, 64);
    vals[q] = x;
  }
  // red[] lives in wave-0's LDS region -> sync all waves' prior reads.
  __syncthreads();
  float* red = (float*)lds2;
  if (lane == 0) {
#pragma unroll
    for (int q = 0; q < 14; ++q) red[q * 8 + w] = vals[q];
  }
  __syncthreads();
  if (tid < 14) {
    float F = 0.f;
#pragma unroll
    for (int ww = 0; ww < 8; ++ww) F += red[tid * 8 + ww];
    float* pt = partials + (size_t)blockIdx.x * 16;
    if (tid == 0) {
      pt[0] = (h & 4) ? -F : F;  // wire 0 <-> h bit 2
      pt[1] = (h & 2) ? -F : F;  // wire 1
      pt[2] = (h & 1) ? -F : F;  // wire 2
    } else {
      pt[tid + 2] = F;           // tid 1..9 -> wires 3..11; 10..13 -> 12..15
    }
  }
}

// ---------------------------------------------------------------------------
__global__ void k_head(const float* __restrict__ partials, const float* __restrict__ w,
                       const float* __restrict__ bh, float* __restrict__ out) {
  int b = threadIdx.x;  // 256 threads
  float acc = bh[0];
  for (int q = 0; q < 16; ++q) {
    float F = 0.f;
    for (int hh = 0; hh < 8; ++hh) F += partials[(size_t)(b * 8 + hh) * 16 + q];
    acc += w[q] * F;
  }
  out[b] = acc;
}

// ---------------------------------------------------------------------------
extern "C" void kernel_launch(void* const* d_in, const int* in_sizes, int n_in,
                              void* d_out, int out_size, void* d_ws, size_t ws_size,
                              hipStream_t stream) {
  const float* state  = (const float*)d_in[0];
  const float* params = (const float*)d_in[1];
  const float* w_head = (const float*)d_in[2];
  const float* b_head = (const float*)d_in[3];
  float* out = (float*)d_out;

  char* ws = (char*)d_ws;
  v2f* st = (v2f*)ws;                                       // 128 MB
  float4* Utab = (float4*)(ws + (size_t)134217728);         // 1 KB
  float* partials = (float*)(ws + (size_t)134217728 + 1024);// 128 KB

  k_setup<<<1, 64, 0, stream>>>(params, Utab);
  k_passA<<<dim3(4096), dim3(NTA), 0, stream>>>(state, Utab, st);
  k_passB<<<dim3(2048), dim3(NTB), 0, stream>>>((const float4*)st, Utab, partials);
  k_head<<<1, 256, 0, stream>>>(partials, w_head, b_head, out);
}